// Round 17
// baseline (224.080 us; speedup 1.0000x reference)
//
#include <hip/hip_runtime.h>
#include <hip/hip_bf16.h>
#include <cstdint>
#include <cstddef>

#define NN 50000
#define NE 800000
#define FD 128
#define NC 40

#define NBKT 196                      // buckets of 256 nodes
#define BSHIFT 8
#define BNODES 256
#define BCAP 4608                     // mean 4082 + 8 sigma
#define CHUNK 2048
#define PA_BLOCKS ((NE + CHUNK - 1) / CHUNK)   // 391

typedef unsigned short u16;
typedef unsigned int u32;
typedef short s16x8 __attribute__((ext_vector_type(8)));
typedef float f32x4 __attribute__((ext_vector_type(4)));

__device__ __forceinline__ float b2f(short h) {
  return __uint_as_float(((unsigned int)(u16)h) << 16);
}
__device__ __forceinline__ u16 f2b(float f) {
  unsigned int u = __float_as_uint(f);
  return (u16)((u + 0x7FFFu + ((u >> 16) & 1u)) >> 16);
}

// async global->LDS, 16B per lane, wave-uniform LDS base + lane*16
__device__ __forceinline__ void gload_lds16(const void* g, void* l) {
  __builtin_amdgcn_global_load_lds(
      (const __attribute__((address_space(1))) void*)g,
      (__attribute__((address_space(3))) void*)l, 16, 0, 0);
}

// ---------------- CSR build: 2-phase LDS binning (packed u32 pairs) ----------------

__global__ __launch_bounds__(256) void binA_kernel(const int* __restrict__ esrc,
                                                   const int* __restrict__ edst,
                                                   int* __restrict__ bcur,
                                                   u32* __restrict__ pairs) {
  __shared__ int lh[NBKT], gbase[NBKT], lcur[NBKT];
  int t = threadIdx.x;
  int e0 = blockIdx.x * CHUNK;
  int e1 = min(e0 + CHUNK, NE);
  if (t < NBKT) lh[t] = 0;
  __syncthreads();
  for (int e = e0 + t; e < e1; e += 256) {
    atomicAdd(&lh[edst[e] >> BSHIFT], 1);
  }
  __syncthreads();
  if (t < NBKT) {
    int c = lh[t];
    gbase[t] = (c > 0) ? atomicAdd(&bcur[t], c) : 0;
    lcur[t] = 0;
  }
  __syncthreads();
  for (int e = e0 + t; e < e1; e += 256) {
    int d = edst[e], s = esrc[e];
    int b = d >> BSHIFT;
    int r = atomicAdd(&lcur[b], 1);
    pairs[(size_t)b * BCAP + gbase[b] + r] = ((u32)(d & (BNODES - 1)) << 16) | (u32)s;
  }
}

__global__ __launch_bounds__(256) void binB_kernel(const int* __restrict__ bcur,
                                                   const u32* __restrict__ pairs,
                                                   int* __restrict__ rowptr,
                                                   float* __restrict__ normv,
                                                   int* __restrict__ col) {
  __shared__ int hist[BNODES], offs[BNODES], sm[BNODES], sbkt[256];
  int b = blockIdx.x, t = threadIdx.x;
  int n0 = b << BSHIFT;

  sbkt[t] = (t < NBKT) ? bcur[t] : 0;
  __syncthreads();
  for (int o = 1; o < 256; o <<= 1) {
    int v = (t >= o) ? sbkt[t - o] : 0;
    __syncthreads();
    sbkt[t] += v;
    __syncthreads();
  }
  int nb = bcur[b];
  int base = sbkt[b] - nb;
  if (b == 0 && t == 0) rowptr[NN] = NE;

  hist[t] = 0;
  __syncthreads();
  const u32* bp = pairs + (size_t)b * BCAP;
  for (int e = t; e < nb; e += 256) {
    atomicAdd(&hist[bp[e] >> 16], 1);
  }
  __syncthreads();
  int v = hist[t];
  sm[t] = v;
  __syncthreads();
  for (int o = 1; o < 256; o <<= 1) {
    int x = (t >= o) ? sm[t - o] : 0;
    __syncthreads();
    sm[t] += x;
    __syncthreads();
  }
  offs[t] = sm[t] - v;
  int node = n0 + t;
  if (node < NN) {
    rowptr[node] = base + offs[t];
    normv[node] = rsqrtf((float)(hist[t] + 1));
  }
  __syncthreads();
  for (int e = t; e < nb; e += 256) {
    u32 p = bp[e];
    int pos = atomicAdd(&offs[p >> 16], 1);
    col[base + pos] = (int)(p & 0xFFFFu);
  }
}

// ---------------- weight transpose -> PRE-SWIZZLED global layout ----------------
__global__ void transw_kernel(const float* __restrict__ Wconv, const float* __restrict__ fc1_w,
                              const float* __restrict__ fc2_w, const float* __restrict__ fc3_w,
                              u16* __restrict__ Wt, u16* __restrict__ W3t,
                              int* __restrict__ bcur) {
  if (blockIdx.x == 0 && blockIdx.y == 0 && threadIdx.x < NBKT) bcur[threadIdx.x] = 0;
  int mat = blockIdx.y;
  int idx = blockIdx.x * 256 + threadIdx.x;
  if (mat < 5) {
    int n = idx >> 7, k = idx & 127;
    const float* W = (mat < 3) ? (Wconv + (size_t)mat * FD * FD) : ((mat == 3) ? fc1_w : fc2_w);
    int byte = (n * FD + k) * 2;
    int sw = byte ^ ((n & 7) << 4);
    *(u16*)((char*)Wt + (size_t)mat * FD * FD * 2 + sw) = f2b(W[k * FD + n]);
  } else {
    if (idx < 48 * FD) {
      int n = idx >> 7, k = idx & 127;
      int byte = (n * FD + k) * 2;
      int sw = byte ^ ((n & 7) << 4);
      *(u16*)((char*)W3t + sw) = (n < NC) ? f2b(fc3_w[k * NC + n]) : (u16)0;
    }
  }
}

// ---------------- bf16 MFMA GEMM, 128-row M-tile, async-staged pre-swizzled B ----------------
// Each wave owns rows [wid*16, wid*16+16) and [wid*16+64, wid*16+80); one
// B-fragment read feeds both row groups' MFMAs.
template <int FUSE, int AF32, int SCALE>
__global__ __launch_bounds__(256) void mfma_gemm(const void* __restrict__ Xv,
                                                 const u16* __restrict__ Wt,
                                                 const float* __restrict__ bias,
                                                 const float* __restrict__ normv,
                                                 u16* __restrict__ out, int M) {
  __shared__ u16 Bs[FD * FD];  // 32 KB, swizzled layout
  int tid = threadIdx.x;
  int wid = tid >> 6;
  int lane = tid & 63;
  int g = lane >> 4, c = lane & 15;
  int mbase0 = blockIdx.x * 128 + wid * 16;
  int mbase1 = mbase0 + 64;

  // stage B: 32 chunks of 1024B via global_load_lds
  {
    const char* gW = (const char*)Wt;
#pragma unroll
    for (int p = 0; p < 8; ++p) {
      int idx = wid * 8 + p;
      gload_lds16(gW + idx * 1024 + lane * 16, (char*)Bs + idx * 1024);
    }
  }

  int arow0 = mbase0 + c; if (arow0 > M - 1) arow0 = M - 1;
  int arow1 = mbase1 + c; if (arow1 > M - 1) arow1 = M - 1;

  s16x8 a0[4], a1[4];
  if (AF32) {
    const float* Xf = (const float*)Xv;
#pragma unroll
    for (int ks = 0; ks < 4; ++ks) {
      const float* p0 = Xf + (size_t)arow0 * FD + ks * 32 + g * 8;
      const float* p1 = Xf + (size_t)arow1 * FD + ks * 32 + g * 8;
      float4 v0 = *(const float4*)p0, v1 = *(const float4*)(p0 + 4);
      float4 w0 = *(const float4*)p1, w1 = *(const float4*)(p1 + 4);
      s16x8 av, bv;
      av[0] = (short)f2b(v0.x); av[1] = (short)f2b(v0.y);
      av[2] = (short)f2b(v0.z); av[3] = (short)f2b(v0.w);
      av[4] = (short)f2b(v1.x); av[5] = (short)f2b(v1.y);
      av[6] = (short)f2b(v1.z); av[7] = (short)f2b(v1.w);
      bv[0] = (short)f2b(w0.x); bv[1] = (short)f2b(w0.y);
      bv[2] = (short)f2b(w0.z); bv[3] = (short)f2b(w0.w);
      bv[4] = (short)f2b(w1.x); bv[5] = (short)f2b(w1.y);
      bv[6] = (short)f2b(w1.z); bv[7] = (short)f2b(w1.w);
      a0[ks] = av; a1[ks] = bv;
    }
  } else {
    const u16* Xb = (const u16*)Xv;
#pragma unroll
    for (int ks = 0; ks < 4; ++ks) {
      a0[ks] = *(const s16x8*)(Xb + (size_t)arow0 * FD + ks * 32 + g * 8);
      a1[ks] = *(const s16x8*)(Xb + (size_t)arow1 * FD + ks * 32 + g * 8);
    }
  }
  __syncthreads();  // drains vmcnt incl. global_load_lds

  f32x4 acc0[8], acc1[8];
#pragma unroll
  for (int n = 0; n < 8; ++n) { acc0[n] = (f32x4)(0.f); acc1[n] = (f32x4)(0.f); }

#pragma unroll
  for (int ks = 0; ks < 4; ++ks) {
#pragma unroll
    for (int n = 0; n < 8; ++n) {
      int row = n * 16 + c;
      int byte = (row * FD + ks * 32 + g * 8) * 2;
      s16x8 b = *(const s16x8*)((const char*)Bs + (byte ^ ((c & 7) << 4)));
      acc0[n] = __builtin_amdgcn_mfma_f32_16x16x32_bf16(a0[ks], b, acc0[n], 0, 0, 0);
      acc1[n] = __builtin_amdgcn_mfma_f32_16x16x32_bf16(a1[ks], b, acc1[n], 0, 0, 0);
    }
  }

  // epilogue (both groups)
#pragma unroll
  for (int grp = 0; grp < 2; ++grp) {
    f32x4* acc = grp ? acc1 : acc0;
    int orow = (grp ? mbase1 : mbase0) + 4 * g;
    float nrm[4];
    if (SCALE) {
#pragma unroll
      for (int r = 0; r < 4; ++r) {
        int rr = orow + r;
        nrm[r] = normv[(rr < M) ? rr : (M - 1)];
      }
    }
#pragma unroll
    for (int n = 0; n < 8; ++n) {
#pragma unroll
      for (int r = 0; r < 4; ++r) {
        int rr = orow + r;
        if (rr < M) {
          float v = acc[n][r];
          if (FUSE) v = fmaxf(v + bias[n * 16 + c], 0.f);
          if (SCALE) v *= nrm[r];
          out[(size_t)rr * FD + n * 16 + c] = f2b(v);
        }
      }
    }
  }
}

// ---------------- GCN aggregation: wave/node, register-resident indices ----------------
__global__ __launch_bounds__(256) void agg_bf16(const u16* __restrict__ hs,
                                                const float* __restrict__ norm,
                                                const int* __restrict__ rowptr,
                                                const int* __restrict__ col,
                                                const float* __restrict__ bias,
                                                const u16* __restrict__ y1,
                                                u16* __restrict__ out) {
  int wid = threadIdx.x >> 6;
  int lane = threadIdx.x & 63;
  int i = blockIdx.x * 4 + wid;
  if (i >= NN) return;
  int g = lane >> 4, c = lane & 15;

  int beg = rowptr[i], end = rowptr[i + 1];
  int deg = end - beg;  // wave-uniform

  int cv = 0;
  if (deg > 0) cv = col[beg + min(lane, deg - 1)];

  float acc[8];
#pragma unroll
  for (int j = 0; j < 8; ++j) acc[j] = 0.f;

  int rounds = (deg + 15) >> 4;
  int dm1 = deg - 1;
  for (int k = 0; k < rounds; ++k) {
    int p = g + (k << 4);
    int p1 = p + 4, p2 = p + 8, p3 = p + 12;
    int q0 = min(p, dm1), q1 = min(p1, dm1), q2 = min(p2, dm1), q3 = min(p3, dm1);
    int s0 = (q0 < 64) ? __shfl(cv, q0) : col[beg + q0];
    int s1 = (q1 < 64) ? __shfl(cv, q1) : col[beg + q1];
    int s2 = (q2 < 64) ? __shfl(cv, q2) : col[beg + q2];
    int s3 = (q3 < 64) ? __shfl(cv, q3) : col[beg + q3];
    s16x8 r0 = *(const s16x8*)(hs + ((size_t)s0 << 7) + c * 8);
    s16x8 r1 = *(const s16x8*)(hs + ((size_t)s1 << 7) + c * 8);
    s16x8 r2 = *(const s16x8*)(hs + ((size_t)s2 << 7) + c * 8);
    s16x8 r3 = *(const s16x8*)(hs + ((size_t)s3 << 7) + c * 8);
    if (p3 < deg) {
#pragma unroll
      for (int j = 0; j < 8; ++j)
        acc[j] += (b2f(r0[j]) + b2f(r1[j])) + (b2f(r2[j]) + b2f(r3[j]));
    } else {
#pragma unroll
      for (int j = 0; j < 8; ++j) {
        float v = 0.f;
        if (p < deg) v += b2f(r0[j]);
        if (p1 < deg) v += b2f(r1[j]);
        if (p2 < deg) v += b2f(r2[j]);
        acc[j] += v;
      }
    }
  }

#pragma unroll
  for (int j = 0; j < 8; ++j) {
    acc[j] += __shfl_xor(acc[j], 16);
    acc[j] += __shfl_xor(acc[j], 32);
  }
  if (g == 0) {
    float ni = norm[i];
    s16x8 self = *(const s16x8*)(hs + ((size_t)i << 7) + c * 8);
    s16x8 res;
    if (y1) res = *(const s16x8*)(y1 + ((size_t)i << 7) + c * 8);
    u16 pk[8];
#pragma unroll
    for (int j = 0; j < 8; ++j) {
      float v = ni * (acc[j] + b2f(self[j])) + bias[c * 8 + j];
      if (y1) v += b2f(res[j]);
      pk[j] = f2b(fmaxf(v, 0.f));
    }
    *(s16x8*)(out + ((size_t)i << 7) + c * 8) = *(s16x8*)pk;
  }
}

// ---------------- fc3 (128 -> 40, padded 48) + log_softmax, async-staged B ----------------
__global__ __launch_bounds__(256) void fc3_mfma(const u16* __restrict__ X,
                                                const u16* __restrict__ W3t,
                                                const float* __restrict__ b3,
                                                float* __restrict__ out, int M) {
  __shared__ u16 Bs[48 * FD];  // 12 KB
  int tid = threadIdx.x;
  int wid = tid >> 6;
  int lane = tid & 63;
  int g = lane >> 4, c = lane & 15;
  int mbase = blockIdx.x * 64 + wid * 16;

  {
    const char* gW = (const char*)W3t;
#pragma unroll
    for (int p = 0; p < 3; ++p) {
      int idx = wid * 3 + p;
      gload_lds16(gW + idx * 1024 + lane * 16, (char*)Bs + idx * 1024);
    }
  }

  int arow = mbase + c;
  if (arow > M - 1) arow = M - 1;
  const u16* aptr = X + (size_t)arow * FD + g * 8;
  s16x8 a[4];
#pragma unroll
  for (int ks = 0; ks < 4; ++ks) a[ks] = *(const s16x8*)(aptr + ks * 32);
  __syncthreads();

  f32x4 acc[3];
#pragma unroll
  for (int n = 0; n < 3; ++n) acc[n] = (f32x4)(0.f);

#pragma unroll
  for (int ks = 0; ks < 4; ++ks) {
#pragma unroll
    for (int n = 0; n < 3; ++n) {
      int row = n * 16 + c;
      int byte = (row * FD + ks * 32 + g * 8) * 2;
      s16x8 b = *(const s16x8*)((const char*)Bs + (byte ^ ((c & 7) << 4)));
      acc[n] = __builtin_amdgcn_mfma_f32_16x16x32_bf16(a[ks], b, acc[n], 0, 0, 0);
    }
  }

  int row0 = mbase + 4 * g;
#pragma unroll
  for (int r = 0; r < 4; ++r) {
    float v0 = acc[0][r] + b3[c];
    float v1 = acc[1][r] + b3[16 + c];
    float v2 = (c < 8) ? (acc[2][r] + b3[32 + c]) : -1e30f;
    float m = fmaxf(fmaxf(v0, v1), v2);
#pragma unroll
    for (int off = 1; off <= 8; off <<= 1) m = fmaxf(m, __shfl_xor(m, off));
    float s = __expf(v0 - m) + __expf(v1 - m) + ((c < 8) ? __expf(v2 - m) : 0.f);
#pragma unroll
    for (int off = 1; off <= 8; off <<= 1) s += __shfl_xor(s, off);
    float lse = m + __logf(s);
    int rr = row0 + r;
    if (rr < M) {
      out[(size_t)rr * NC + c] = v0 - lse;
      out[(size_t)rr * NC + 16 + c] = v1 - lse;
      if (c < 8) out[(size_t)rr * NC + 32 + c] = v2 - lse;
    }
  }
}

// ---------------- launch ----------------

extern "C" void kernel_launch(void* const* d_in, const int* in_sizes, int n_in,
                              void* d_out, int out_size, void* d_ws, size_t ws_size,
                              hipStream_t stream) {
  const float* x = (const float*)d_in[0];
  const float* Wconv = (const float*)d_in[1];
  const float* bconv = (const float*)d_in[2];
  const float* fc1_w = (const float*)d_in[3];
  const float* fc1_b = (const float*)d_in[4];
  const float* fc2_w = (const float*)d_in[5];
  const float* fc2_b = (const float*)d_in[6];
  const float* fc3_w = (const float*)d_in[7];
  const float* fc3_b = (const float*)d_in[8];
  const int* edge = (const int*)d_in[9];
  const int* esrc = edge;
  const int* edst = edge + NE;

  uint8_t* w = (uint8_t*)d_ws;
  size_t off = 0;
  auto take = [&](size_t bytes) -> void* {
    void* p = w + off;
    off += (bytes + 255) & ~(size_t)255;
    return p;
  };
  float* norm = (float*)take((size_t)NN * 4);
  int* rowptr = (int*)take((size_t)(NN + 1) * 4);
  int* bcur = (int*)take(256 * 4);
  u32* pairs = (u32*)take((size_t)NBKT * BCAP * 4);
  int* col = (int*)take((size_t)NE * 4);
  u16* Wt = (u16*)take((size_t)5 * FD * FD * 2);
  u16* W3t = (u16*)take((size_t)48 * FD * 2);
  u16* h = (u16*)take((size_t)NN * FD * 2);
  u16* y = (u16*)take((size_t)NN * FD * 2);
  u16* y1 = (u16*)take((size_t)NN * FD * 2);

  transw_kernel<<<dim3(64, 6), 256, 0, stream>>>(Wconv, fc1_w, fc2_w, fc3_w, Wt, W3t, bcur);
  binA_kernel<<<PA_BLOCKS, 256, 0, stream>>>(esrc, edst, bcur, pairs);
  binB_kernel<<<NBKT, 256, 0, stream>>>(bcur, pairs, rowptr, norm, col);

  const int GB = (NN + 127) / 128;  // 391 (128-row M-tile)
  const int AB = (NN + 3) / 4;      // 12500

  // conv layer 1 (fp32 x in, scaled hs out)
  mfma_gemm<0, 1, 1><<<GB, 256, 0, stream>>>(x, Wt, nullptr, norm, h, NN);
  agg_bf16<<<AB, 256, 0, stream>>>(h, norm, rowptr, col, bconv, nullptr, y1);
  // conv layer 2
  mfma_gemm<0, 0, 1><<<GB, 256, 0, stream>>>(y1, Wt + FD * FD, nullptr, norm, h, NN);
  agg_bf16<<<AB, 256, 0, stream>>>(h, norm, rowptr, col, bconv + FD, y1, y);
  // conv layer 3
  mfma_gemm<0, 0, 1><<<GB, 256, 0, stream>>>(y, Wt + 2 * FD * FD, nullptr, norm, h, NN);
  agg_bf16<<<AB, 256, 0, stream>>>(h, norm, rowptr, col, bconv + 2 * FD, y1, y);

  // fc1, fc2 (bias+relu fused), fc3+log_softmax
  mfma_gemm<1, 0, 0><<<GB, 256, 0, stream>>>(y, Wt + 3 * FD * FD, fc1_b, nullptr, h, NN);
  mfma_gemm<1, 0, 0><<<GB, 256, 0, stream>>>(h, Wt + 4 * FD * FD, fc2_b, nullptr, y1, NN);
  fc3_mfma<<<(NN + 63) / 64, 256, 0, stream>>>(y1, W3t, fc3_b, (float*)d_out, NN);
}

// Round 19
// 207.220 us; speedup vs baseline: 1.0814x; 1.0814x over previous
//
#include <hip/hip_runtime.h>
#include <hip/hip_bf16.h>
#include <cstdint>
#include <cstddef>

#define NN 50000
#define NE 800000
#define FD 128
#define NC 40

#define NBKT 196                      // buckets of 256 nodes
#define BSHIFT 8
#define BNODES 256
#define BCAP 4608                     // mean 4082 + 8 sigma
#define CHUNK 2048
#define PA_BLOCKS ((NE + CHUNK - 1) / CHUNK)   // 391

typedef unsigned short u16;
typedef unsigned int u32;
typedef short s16x8 __attribute__((ext_vector_type(8)));
typedef float f32x4 __attribute__((ext_vector_type(4)));

__device__ __forceinline__ float b2f(short h) {
  return __uint_as_float(((unsigned int)(u16)h) << 16);
}
__device__ __forceinline__ u16 f2b(float f) {
  unsigned int u = __float_as_uint(f);
  return (u16)((u + 0x7FFFu + ((u >> 16) & 1u)) >> 16);
}

// ---------------- CSR build: 2-phase LDS binning (packed u32 pairs) ----------------

__global__ __launch_bounds__(256) void binA_kernel(const int* __restrict__ esrc,
                                                   const int* __restrict__ edst,
                                                   int* __restrict__ bcur,
                                                   u32* __restrict__ pairs) {
  __shared__ int lh[NBKT], gbase[NBKT], lcur[NBKT];
  int t = threadIdx.x;
  int e0 = blockIdx.x * CHUNK;
  int e1 = min(e0 + CHUNK, NE);
  if (t < NBKT) lh[t] = 0;
  __syncthreads();
  for (int e = e0 + t; e < e1; e += 256) {
    atomicAdd(&lh[edst[e] >> BSHIFT], 1);
  }
  __syncthreads();
  if (t < NBKT) {
    int c = lh[t];
    gbase[t] = (c > 0) ? atomicAdd(&bcur[t], c) : 0;
    lcur[t] = 0;
  }
  __syncthreads();
  for (int e = e0 + t; e < e1; e += 256) {
    int d = edst[e], s = esrc[e];
    int b = d >> BSHIFT;
    int r = atomicAdd(&lcur[b], 1);
    pairs[(size_t)b * BCAP + gbase[b] + r] = ((u32)(d & (BNODES - 1)) << 16) | (u32)s;
  }
}

__global__ __launch_bounds__(256) void binB_kernel(const int* __restrict__ bcur,
                                                   const u32* __restrict__ pairs,
                                                   int* __restrict__ rowptr,
                                                   float* __restrict__ normv,
                                                   int* __restrict__ col) {
  __shared__ int hist[BNODES], offs[BNODES], sm[BNODES], sbkt[256];
  int b = blockIdx.x, t = threadIdx.x;
  int n0 = b << BSHIFT;

  sbkt[t] = (t < NBKT) ? bcur[t] : 0;
  __syncthreads();
  for (int o = 1; o < 256; o <<= 1) {
    int v = (t >= o) ? sbkt[t - o] : 0;
    __syncthreads();
    sbkt[t] += v;
    __syncthreads();
  }
  int nb = bcur[b];
  int base = sbkt[b] - nb;
  if (b == 0 && t == 0) rowptr[NN] = NE;

  hist[t] = 0;
  __syncthreads();
  const u32* bp = pairs + (size_t)b * BCAP;
  for (int e = t; e < nb; e += 256) {
    atomicAdd(&hist[bp[e] >> 16], 1);
  }
  __syncthreads();
  int v = hist[t];
  sm[t] = v;
  __syncthreads();
  for (int o = 1; o < 256; o <<= 1) {
    int x = (t >= o) ? sm[t - o] : 0;
    __syncthreads();
    sm[t] += x;
    __syncthreads();
  }
  offs[t] = sm[t] - v;
  int node = n0 + t;
  if (node < NN) {
    rowptr[node] = base + offs[t];
    normv[node] = rsqrtf((float)(hist[t] + 1));
  }
  __syncthreads();
  for (int e = t; e < nb; e += 256) {
    u32 p = bp[e];
    int pos = atomicAdd(&offs[p >> 16], 1);
    col[base + pos] = (int)(p & 0xFFFFu);
  }
}

// ---------------- weight transpose (+ zero bcur; runs first) ----------------
__global__ void transw_kernel(const float* __restrict__ Wconv, const float* __restrict__ fc1_w,
                              const float* __restrict__ fc2_w, const float* __restrict__ fc3_w,
                              u16* __restrict__ Wt, u16* __restrict__ W3t,
                              int* __restrict__ bcur) {
  if (blockIdx.x == 0 && blockIdx.y == 0 && threadIdx.x < NBKT) bcur[threadIdx.x] = 0;
  int mat = blockIdx.y;
  int idx = blockIdx.x * 256 + threadIdx.x;
  if (mat < 5) {
    int n = idx >> 7, k = idx & 127;
    const float* W = (mat < 3) ? (Wconv + (size_t)mat * FD * FD) : ((mat == 3) ? fc1_w : fc2_w);
    Wt[(size_t)mat * FD * FD + n * FD + k] = f2b(W[k * FD + n]);
  } else {
    if (idx < 48 * FD) {
      int n = idx >> 7, k = idx & 127;
      W3t[n * FD + k] = (n < NC) ? f2b(fc3_w[k * NC + n]) : (u16)0;
    }
  }
}

// ---------------- bf16 MFMA GEMM with LDS-staged, XOR-swizzled B ----------------
template <int FUSE, int AF32, int SCALE>
__global__ __launch_bounds__(256) void mfma_gemm(const void* __restrict__ Xv,
                                                 const u16* __restrict__ Wt,
                                                 const float* __restrict__ bias,
                                                 const float* __restrict__ normv,
                                                 u16* __restrict__ out, int M) {
  __shared__ u16 Bs[FD * FD];  // 32 KB
  int tid = threadIdx.x;
  int wid = tid >> 6;
  int lane = tid & 63;
  int g = lane >> 4, c = lane & 15;
  int mbase = blockIdx.x * 64 + wid * 16;

  // stage B: 2048 chunks of 16B, XOR-swizzled (byte ^= (row&7)<<4)
#pragma unroll
  for (int p = 0; p < 8; ++p) {
    int idx = p * 256 + tid;
    int row = idx >> 4, c8 = idx & 15;
    int byte = (row * FD + c8 * 8) * 2;
    int sw = byte ^ ((row & 7) << 4);
    *(s16x8*)((char*)Bs + sw) = *(const s16x8*)(Wt + row * FD + c8 * 8);
  }

  int arow = mbase + c;
  if (arow > M - 1) arow = M - 1;

  s16x8 a[4];
  if (AF32) {
    const float* Xf = (const float*)Xv;
#pragma unroll
    for (int ks = 0; ks < 4; ++ks) {
      const float* p = Xf + (size_t)arow * FD + ks * 32 + g * 8;
      float4 v0 = *(const float4*)p;
      float4 v1 = *(const float4*)(p + 4);
      s16x8 av;
      av[0] = (short)f2b(v0.x); av[1] = (short)f2b(v0.y);
      av[2] = (short)f2b(v0.z); av[3] = (short)f2b(v0.w);
      av[4] = (short)f2b(v1.x); av[5] = (short)f2b(v1.y);
      av[6] = (short)f2b(v1.z); av[7] = (short)f2b(v1.w);
      a[ks] = av;
    }
  } else {
    const u16* Xb = (const u16*)Xv;
#pragma unroll
    for (int ks = 0; ks < 4; ++ks)
      a[ks] = *(const s16x8*)(Xb + (size_t)arow * FD + ks * 32 + g * 8);
  }
  __syncthreads();

  f32x4 acc[8];
#pragma unroll
  for (int n = 0; n < 8; ++n) acc[n] = (f32x4)(0.f);

#pragma unroll
  for (int ks = 0; ks < 4; ++ks) {
#pragma unroll
    for (int n = 0; n < 8; ++n) {
      int row = n * 16 + c;
      int byte = (row * FD + ks * 32 + g * 8) * 2;
      s16x8 b = *(const s16x8*)((const char*)Bs + (byte ^ ((c & 7) << 4)));
      acc[n] = __builtin_amdgcn_mfma_f32_16x16x32_bf16(a[ks], b, acc[n], 0, 0, 0);
    }
  }

  int orow = mbase + 4 * g;
  float nrm[4];
  if (SCALE) {
#pragma unroll
    for (int r = 0; r < 4; ++r) {
      int rr = orow + r;
      nrm[r] = normv[(rr < M) ? rr : (M - 1)];
    }
  }
#pragma unroll
  for (int n = 0; n < 8; ++n) {
#pragma unroll
    for (int r = 0; r < 4; ++r) {
      int rr = orow + r;
      if (rr < M) {
        float v = acc[n][r];
        if (FUSE) v = fmaxf(v + bias[n * 16 + c], 0.f);
        if (SCALE) v *= nrm[r];
        out[(size_t)rr * FD + n * 16 + c] = f2b(v);
      }
    }
  }
}

// ---------------- GCN aggregation: wave/node, register-resident indices ----------------
__global__ __launch_bounds__(256) void agg_bf16(const u16* __restrict__ hs,
                                                const float* __restrict__ norm,
                                                const int* __restrict__ rowptr,
                                                const int* __restrict__ col,
                                                const float* __restrict__ bias,
                                                const u16* __restrict__ y1,
                                                u16* __restrict__ out) {
  int wid = threadIdx.x >> 6;
  int lane = threadIdx.x & 63;
  int i = blockIdx.x * 4 + wid;
  if (i >= NN) return;
  int g = lane >> 4, c = lane & 15;

  int beg = rowptr[i], end = rowptr[i + 1];
  int deg = end - beg;  // wave-uniform

  int cv = 0;
  if (deg > 0) cv = col[beg + min(lane, deg - 1)];

  float acc[8];
#pragma unroll
  for (int j = 0; j < 8; ++j) acc[j] = 0.f;

  int rounds = (deg + 15) >> 4;
  int dm1 = deg - 1;
  for (int k = 0; k < rounds; ++k) {
    int p = g + (k << 4);
    int p1 = p + 4, p2 = p + 8, p3 = p + 12;
    int q0 = min(p, dm1), q1 = min(p1, dm1), q2 = min(p2, dm1), q3 = min(p3, dm1);
    int s0 = (q0 < 64) ? __shfl(cv, q0) : col[beg + q0];
    int s1 = (q1 < 64) ? __shfl(cv, q1) : col[beg + q1];
    int s2 = (q2 < 64) ? __shfl(cv, q2) : col[beg + q2];
    int s3 = (q3 < 64) ? __shfl(cv, q3) : col[beg + q3];
    s16x8 r0 = *(const s16x8*)(hs + ((size_t)s0 << 7) + c * 8);
    s16x8 r1 = *(const s16x8*)(hs + ((size_t)s1 << 7) + c * 8);
    s16x8 r2 = *(const s16x8*)(hs + ((size_t)s2 << 7) + c * 8);
    s16x8 r3 = *(const s16x8*)(hs + ((size_t)s3 << 7) + c * 8);
    if (p3 < deg) {
#pragma unroll
      for (int j = 0; j < 8; ++j)
        acc[j] += (b2f(r0[j]) + b2f(r1[j])) + (b2f(r2[j]) + b2f(r3[j]));
    } else {
#pragma unroll
      for (int j = 0; j < 8; ++j) {
        float v = 0.f;
        if (p < deg) v += b2f(r0[j]);
        if (p1 < deg) v += b2f(r1[j]);
        if (p2 < deg) v += b2f(r2[j]);
        acc[j] += v;
      }
    }
  }

#pragma unroll
  for (int j = 0; j < 8; ++j) {
    acc[j] += __shfl_xor(acc[j], 16);
    acc[j] += __shfl_xor(acc[j], 32);
  }
  if (g == 0) {
    float ni = norm[i];
    s16x8 self = *(const s16x8*)(hs + ((size_t)i << 7) + c * 8);
    s16x8 res;
    if (y1) res = *(const s16x8*)(y1 + ((size_t)i << 7) + c * 8);
    u16 pk[8];
#pragma unroll
    for (int j = 0; j < 8; ++j) {
      float v = ni * (acc[j] + b2f(self[j])) + bias[c * 8 + j];
      if (y1) v += b2f(res[j]);
      pk[j] = f2b(fmaxf(v, 0.f));
    }
    *(s16x8*)(out + ((size_t)i << 7) + c * 8) = *(s16x8*)pk;
  }
}

// ---------------- fc3 (128 -> 40, padded 48) + log_softmax, LDS-staged B ----------------
__global__ __launch_bounds__(256) void fc3_mfma(const u16* __restrict__ X,
                                                const u16* __restrict__ W3t,
                                                const float* __restrict__ b3,
                                                float* __restrict__ out, int M) {
  __shared__ u16 Bs[48 * FD];  // 12 KB
  int tid = threadIdx.x;
  int wid = tid >> 6;
  int lane = tid & 63;
  int g = lane >> 4, c = lane & 15;
  int mbase = blockIdx.x * 64 + wid * 16;

#pragma unroll
  for (int p = 0; p < 3; ++p) {
    int idx = p * 256 + tid;
    if (idx < 48 * 16) {
      int row = idx >> 4, c8 = idx & 15;
      int byte = (row * FD + c8 * 8) * 2;
      int sw = byte ^ ((row & 7) << 4);
      *(s16x8*)((char*)Bs + sw) = *(const s16x8*)(W3t + row * FD + c8 * 8);
    }
  }

  int arow = mbase + c;
  if (arow > M - 1) arow = M - 1;
  const u16* aptr = X + (size_t)arow * FD + g * 8;
  s16x8 a[4];
#pragma unroll
  for (int ks = 0; ks < 4; ++ks) a[ks] = *(const s16x8*)(aptr + ks * 32);
  __syncthreads();

  f32x4 acc[3];
#pragma unroll
  for (int n = 0; n < 3; ++n) acc[n] = (f32x4)(0.f);

#pragma unroll
  for (int ks = 0; ks < 4; ++ks) {
#pragma unroll
    for (int n = 0; n < 3; ++n) {
      int row = n * 16 + c;
      int byte = (row * FD + ks * 32 + g * 8) * 2;
      s16x8 b = *(const s16x8*)((const char*)Bs + (byte ^ ((c & 7) << 4)));
      acc[n] = __builtin_amdgcn_mfma_f32_16x16x32_bf16(a[ks], b, acc[n], 0, 0, 0);
    }
  }

  int row0 = mbase + 4 * g;
#pragma unroll
  for (int r = 0; r < 4; ++r) {
    float v0 = acc[0][r] + b3[c];
    float v1 = acc[1][r] + b3[16 + c];
    float v2 = (c < 8) ? (acc[2][r] + b3[32 + c]) : -1e30f;
    float m = fmaxf(fmaxf(v0, v1), v2);
#pragma unroll
    for (int off = 1; off <= 8; off <<= 1) m = fmaxf(m, __shfl_xor(m, off));
    float s = __expf(v0 - m) + __expf(v1 - m) + ((c < 8) ? __expf(v2 - m) : 0.f);
#pragma unroll
    for (int off = 1; off <= 8; off <<= 1) s += __shfl_xor(s, off);
    float lse = m + __logf(s);
    int rr = row0 + r;
    if (rr < M) {
      out[(size_t)rr * NC + c] = v0 - lse;
      out[(size_t)rr * NC + 16 + c] = v1 - lse;
      if (c < 8) out[(size_t)rr * NC + 32 + c] = v2 - lse;
    }
  }
}

// ---------------- launch ----------------

extern "C" void kernel_launch(void* const* d_in, const int* in_sizes, int n_in,
                              void* d_out, int out_size, void* d_ws, size_t ws_size,
                              hipStream_t stream) {
  const float* x = (const float*)d_in[0];
  const float* Wconv = (const float*)d_in[1];
  const float* bconv = (const float*)d_in[2];
  const float* fc1_w = (const float*)d_in[3];
  const float* fc1_b = (const float*)d_in[4];
  const float* fc2_w = (const float*)d_in[5];
  const float* fc2_b = (const float*)d_in[6];
  const float* fc3_w = (const float*)d_in[7];
  const float* fc3_b = (const float*)d_in[8];
  const int* edge = (const int*)d_in[9];
  const int* esrc = edge;
  const int* edst = edge + NE;

  uint8_t* w = (uint8_t*)d_ws;
  size_t off = 0;
  auto take = [&](size_t bytes) -> void* {
    void* p = w + off;
    off += (bytes + 255) & ~(size_t)255;
    return p;
  };
  float* norm = (float*)take((size_t)NN * 4);
  int* rowptr = (int*)take((size_t)(NN + 1) * 4);
  int* bcur = (int*)take(256 * 4);
  u32* pairs = (u32*)take((size_t)NBKT * BCAP * 4);
  int* col = (int*)take((size_t)NE * 4);
  u16* Wt = (u16*)take((size_t)5 * FD * FD * 2);
  u16* W3t = (u16*)take((size_t)48 * FD * 2);
  u16* h = (u16*)take((size_t)NN * FD * 2);
  u16* y = (u16*)take((size_t)NN * FD * 2);
  u16* y1 = (u16*)take((size_t)NN * FD * 2);

  transw_kernel<<<dim3(64, 6), 256, 0, stream>>>(Wconv, fc1_w, fc2_w, fc3_w, Wt, W3t, bcur);
  binA_kernel<<<PA_BLOCKS, 256, 0, stream>>>(esrc, edst, bcur, pairs);
  binB_kernel<<<NBKT, 256, 0, stream>>>(bcur, pairs, rowptr, norm, col);

  const int GB = (NN + 63) / 64;  // 782
  const int AB = (NN + 3) / 4;    // 12500

  // conv layer 1 (fp32 x in, scaled hs out)
  mfma_gemm<0, 1, 1><<<GB, 256, 0, stream>>>(x, Wt, nullptr, norm, h, NN);
  agg_bf16<<<AB, 256, 0, stream>>>(h, norm, rowptr, col, bconv, nullptr, y1);
  // conv layer 2
  mfma_gemm<0, 0, 1><<<GB, 256, 0, stream>>>(y1, Wt + FD * FD, nullptr, norm, h, NN);
  agg_bf16<<<AB, 256, 0, stream>>>(h, norm, rowptr, col, bconv + FD, y1, y);
  // conv layer 3
  mfma_gemm<0, 0, 1><<<GB, 256, 0, stream>>>(y, Wt + 2 * FD * FD, nullptr, norm, h, NN);
  agg_bf16<<<AB, 256, 0, stream>>>(h, norm, rowptr, col, bconv + 2 * FD, y1, y);

  // fc1, fc2 (bias+relu fused), fc3+log_softmax
  mfma_gemm<1, 0, 0><<<GB, 256, 0, stream>>>(y, Wt + 3 * FD * FD, fc1_b, nullptr, h, NN);
  mfma_gemm<1, 0, 0><<<GB, 256, 0, stream>>>(h, Wt + 4 * FD * FD, fc2_b, nullptr, y1, NN);
  fc3_mfma<<<(NN + 63) / 64, 256, 0, stream>>>(y1, W3t, fc3_b, (float*)d_out, NN);
}